// Round 1
// 3963.967 us; speedup vs baseline: 1.2699x; 1.2699x over previous
//
#include <hip/hip_runtime.h>
#include <hip/hip_bf16.h>

#define B_   64
#define T_   128
#define IN_  1024
#define H_   2048
#define H4_  8192
#define BT_  8192                 // B_*T_
#define BTH_ 16777216LL           // B_*T_*H_

typedef __attribute__((ext_vector_type(8))) short short8;   // 8 bf16 = 4 VGPRs
typedef __attribute__((ext_vector_type(4))) float f32x4;

__device__ __forceinline__ unsigned short f32_to_bf16_rne(float f) {
    union { float f; unsigned int u; } v; v.f = f;
    return (unsigned short)((v.u + 0x7fffu + ((v.u >> 16) & 1u)) >> 16);
}

// async global->LDS, 16B per lane. LDS dest = wave-uniform base + lane*16.
__device__ __forceinline__ void gload_lds16(const unsigned short* g, unsigned short* l) {
    __builtin_amdgcn_global_load_lds(
        (const __attribute__((address_space(1))) unsigned int*)g,
        (__attribute__((address_space(3))) unsigned int*)l,
        16, 0, 0);
}

// ---------- fp32 -> bf16 conversion (vectorized, grid-stride) ----------
__global__ void cvt_bf16_kernel(const float* __restrict__ src,
                                unsigned short* __restrict__ dst, long n) {
    long i = ((long)blockIdx.x * blockDim.x + threadIdx.x) * 4;
    long stride = (long)gridDim.x * blockDim.x * 4;
    for (; i < n; i += stride) {
        float4 v = *reinterpret_cast<const float4*>(src + i);
        ushort4 o;
        o.x = f32_to_bf16_rne(v.x);
        o.y = f32_to_bf16_rne(v.y);
        o.z = f32_to_bf16_rne(v.z);
        o.w = f32_to_bf16_rne(v.w);
        *reinterpret_cast<ushort4*>(dst + i) = o;
    }
}

__global__ void copy_f32_kernel(const float* __restrict__ src,
                                float* __restrict__ dst, long n) {
    long i = ((long)blockIdx.x * blockDim.x + threadIdx.x) * 4;
    long stride = (long)gridDim.x * blockDim.x * 4;
    for (; i < n; i += stride)
        *reinterpret_cast<float4*>(dst + i) =
            *reinterpret_cast<const float4*>(src + i);
}

// ---------- Phase 1: Yx = x @ Wx^T + b  (m97-structure 128x128 LDS-staged GEMM)
// 256 threads = 4 waves (2x2). Wave tile 64x64 = 4x4 MFMA 16x16x32 acc.
// Per K-step (BK=32): stage A[128][32], B[128][32] via global_load_lds (16B),
// barrier, 8 ds_read_b128 frags, 16 MFMA, barrier.
// MFMA conventions (verified by previous passing kernel):
//   A-frag: lane holds A[row=col][k=quad*8+j]; B-frag: W[n=col][k=quad*8+j];
//   C/D:    col=lane&15, row=quad*4+reg.
__global__ __launch_bounds__(256) void gemm_yx(
    const unsigned short* __restrict__ Xb,    // [BT_, IN_] bf16
    const unsigned short* __restrict__ Wxb,   // [H4_, IN_] bf16
    const float* __restrict__ bias,           // [H4_]
    float* __restrict__ out)                  // d_out base
{
    // XCD-aware swizzle: 4096 blocks, 4096 % 8 == 0 -> simple bijective remap
    int bid = blockIdx.x;
    int sw  = (bid & 7) * 512 + (bid >> 3);
    int nb  = sw & 63;          // N/128 = 64
    int mb  = sw >> 6;          // M/128 = 64
    int m0  = mb * 128;
    int n0  = nb * 128;

    int tid  = threadIdx.x;
    int wave = tid >> 6;
    int lane = tid & 63;
    int col  = lane & 15;
    int quad = lane >> 4;
    int wm   = wave >> 1;       // wave row (0..1)
    int wn   = wave & 1;        // wave col (0..1)

    __shared__ unsigned short As[128 * 32];   // 8 KB
    __shared__ unsigned short Bs[128 * 32];   // 8 KB

    f32x4 acc[4][4];
#pragma unroll
    for (int i = 0; i < 4; i++)
#pragma unroll
        for (int j = 0; j < 4; j++) acc[i][j] = (f32x4){0.f, 0.f, 0.f, 0.f};

    for (int k0 = 0; k0 < IN_; k0 += 32) {
        // ---- stage: each thread 2x16B for A, 2x16B for B ----
#pragma unroll
        for (int r = 0; r < 2; r++) {
            int idx = r * 256 + tid;            // 0..511
            int row = idx >> 2;                 // 0..127
            int c8  = (idx & 3) * 8;            // k sub-offset (elems)
            int dbase = (r * 256 + wave * 64) * 8;   // wave-uniform elem base
            gload_lds16(Xb  + (size_t)(m0 + row) * IN_ + k0 + c8, &As[dbase]);
            gload_lds16(Wxb + (size_t)(n0 + row) * IN_ + k0 + c8, &Bs[dbase]);
        }
        __syncthreads();   // drains vmcnt -> LDS tiles valid

        // ---- frags + 16 MFMA ----
        short8 af[4], bf[4];
#pragma unroll
        for (int mt = 0; mt < 4; mt++)
            af[mt] = *(const short8*)&As[(wm * 64 + mt * 16 + col) * 32 + quad * 8];
#pragma unroll
        for (int nt = 0; nt < 4; nt++)
            bf[nt] = *(const short8*)&Bs[(wn * 64 + nt * 16 + col) * 32 + quad * 8];
#pragma unroll
        for (int mt = 0; mt < 4; mt++)
#pragma unroll
            for (int nt = 0; nt < 4; nt++)
                acc[mt][nt] = __builtin_amdgcn_mfma_f32_16x16x32_bf16(
                    af[mt], bf[nt], acc[mt][nt], 0, 0, 0);
        __syncthreads();   // all waves done reading before next stage
    }

    // ---- epilogue: bias add, write into yi/yf/yg/yo slabs ----
#pragma unroll
    for (int nt = 0; nt < 4; nt++) {
        int n = n0 + wn * 64 + nt * 16 + col;
        int g = n >> 11;
        int h = n & 2047;
        float bv = bias[n];
        float* slab = out + (size_t)(2 + g) * BTH_ + h;
#pragma unroll
        for (int mt = 0; mt < 4; mt++)
#pragma unroll
            for (int r = 0; r < 4; r++) {
                int m = m0 + wm * 64 + mt * 16 + quad * 4 + r;   // m = b*T + t
                slab[(size_t)m * H_] = acc[mt][nt][r] + bv;
            }
    }
}

// ---------- Per-step: y += a_prev @ Wa^T; activations; state update ----------
// Grid: 256 blocks x 512 threads (8 waves = 2/SIMD).
// Block j: m-half = j&1 (32 rows of B), h-tile = j>>1 (16 hidden cols).
// Wave w: gate g = w&3, K-half kh = w>>2. Each wave: 32x16 tile over K=1024.
// K-halves reduced through LDS; activation fused as before.
__global__ __launch_bounds__(512) void lstm_step(
    const unsigned short* __restrict__ Wab,      // [H4_, H_] bf16
    const unsigned short* __restrict__ a_prev,   // [B_, H_] bf16
    float* __restrict__ c_state,                 // [B_, H_] fp32 in/out
    unsigned short* __restrict__ a_next,         // [B_, H_] bf16
    float* __restrict__ out,                     // d_out base
    int t)
{
    int j    = blockIdx.x;
    int mh   = j & 1;
    int ht   = j >> 1;
    int h0   = ht * 16;
    int m0   = mh * 32;
    int w    = threadIdx.x >> 6;
    int g    = w & 3;            // gate
    int kh   = w >> 2;           // K-half
    int lane = threadIdx.x & 63;
    int col  = lane & 15;
    int quad = lane >> 4;

    const unsigned short* brow =
        Wab + (size_t)(g * H_ + h0 + col) * H_ + kh * 1024;
    const unsigned short* arow0 =
        a_prev + (size_t)(m0 + col) * H_ + kh * 1024;
    const unsigned short* arow1 =
        a_prev + (size_t)(m0 + 16 + col) * H_ + kh * 1024;

    f32x4 acc[2];
    acc[0] = (f32x4){0.f, 0.f, 0.f, 0.f};
    acc[1] = acc[0];

#pragma unroll 4
    for (int k0 = 0; k0 < 1024; k0 += 32) {
        short8 bfrag = *(const short8*)(brow  + k0 + quad * 8);
        short8 af0   = *(const short8*)(arow0 + k0 + quad * 8);
        short8 af1   = *(const short8*)(arow1 + k0 + quad * 8);
        acc[0] = __builtin_amdgcn_mfma_f32_16x16x32_bf16(af0, bfrag, acc[0], 0, 0, 0);
        acc[1] = __builtin_amdgcn_mfma_f32_16x16x32_bf16(af1, bfrag, acc[1], 0, 0, 0);
    }

    // partials -> LDS (both K-halves write their own buffer; activation sums)
    __shared__ float yt[2][4][32][17];   // [kh][gate][m-local][h-local], +1 pad
#pragma unroll
    for (int mt = 0; mt < 2; mt++)
#pragma unroll
        for (int r = 0; r < 4; r++) {
            int lm = mt * 16 + quad * 4 + r;     // 0..31
            yt[kh][g][lm][col] = acc[mt][r];
        }
    __syncthreads();

    // Activation: 32 rows x 16 cols = 512 cells; exactly 1 per thread.
    int f  = threadIdx.x;        // 0..511
    int lm = f >> 4;
    int hl = f & 15;
    int b  = m0 + lm;
    int h  = h0 + hl;
    long long oidx = ((long long)b * T_ + t) * H_ + h;

    float yi = yt[0][0][lm][hl] + yt[1][0][lm][hl] + out[2 * BTH_ + oidx];
    float yf = yt[0][1][lm][hl] + yt[1][1][lm][hl] + out[3 * BTH_ + oidx];
    float yg = yt[0][2][lm][hl] + yt[1][2][lm][hl] + out[4 * BTH_ + oidx];
    float yo = yt[0][3][lm][hl] + yt[1][3][lm][hl] + out[5 * BTH_ + oidx];
    out[2 * BTH_ + oidx] = yi;
    out[3 * BTH_ + oidx] = yf;
    out[4 * BTH_ + oidx] = yg;
    out[5 * BTH_ + oidx] = yo;

    float cp = c_state[b * H_ + h];
    float si = 1.f / (1.f + __expf(-yi));
    float sf = 1.f / (1.f + __expf(-yf));
    float so = 1.f / (1.f + __expf(-yo));
    float tg = tanhf(yg);
    float ct = sf * cp + si * tg;
    float at = so * tanhf(ct);

    c_state[b * H_ + h] = ct;
    out[oidx]          = at;     // a slab
    out[BTH_ + oidx]   = ct;     // c slab
    a_next[b * H_ + h] = f32_to_bf16_rne(at);
}

extern "C" void kernel_launch(void* const* d_in, const int* in_sizes, int n_in,
                              void* d_out, int out_size, void* d_ws, size_t ws_size,
                              hipStream_t stream) {
    const float* x    = (const float*)d_in[0];   // [B,T,IN]
    const float* Wx   = (const float*)d_in[1];   // [4H,IN]
    const float* Wa   = (const float*)d_in[2];   // [4H,H]
    const float* bias = (const float*)d_in[3];   // [4H]
    const float* a0   = (const float*)d_in[4];   // [B,H]
    const float* c0   = (const float*)d_in[5];   // [B,H]
    float* out = (float*)d_out;

    // workspace layout (bf16 = unsigned short)
    unsigned short* xb    = (unsigned short*)d_ws;          // BT_*IN_
    unsigned short* wxb   = xb  + (size_t)BT_ * IN_;        // H4_*IN_
    unsigned short* wab   = wxb + (size_t)H4_ * IN_;        // H4_*H_
    unsigned short* abuf0 = wab + (size_t)H4_ * H_;         // B_*H_
    unsigned short* abuf1 = abuf0 + (size_t)B_ * H_;        // B_*H_
    float*          cst   = (float*)(abuf1 + (size_t)B_ * H_);

    cvt_bf16_kernel<<<2048, 256, 0, stream>>>(x,  xb,  (long)BT_ * IN_);
    cvt_bf16_kernel<<<2048, 256, 0, stream>>>(Wx, wxb, (long)H4_ * IN_);
    cvt_bf16_kernel<<<2048, 256, 0, stream>>>(Wa, wab, (long)H4_ * H_);
    cvt_bf16_kernel<<<128,  256, 0, stream>>>(a0, abuf0, (long)B_ * H_);
    copy_f32_kernel<<<128,  256, 0, stream>>>(c0, cst,   (long)B_ * H_);

    gemm_yx<<<(BT_ / 128) * (H4_ / 128), 256, 0, stream>>>(xb, wxb, bias, out);

    for (int t = 0; t < T_; ++t) {
        const unsigned short* ap = (t & 1) ? abuf1 : abuf0;
        unsigned short*       an = (t & 1) ? abuf0 : abuf1;
        lstm_step<<<256, 512, 0, stream>>>(wab, ap, cst, an, out, t);
    }
}